// Round 6
// baseline (1196.404 us; speedup 1.0000x reference)
//
#include <hip/hip_runtime.h>

// F2FConv3d on MI355X.
// contrib[t,o] = sum_kb bary[t,kb] * (W_kb · x[t])  — per-kb MFMA accumulation, bary
// folded in f32 AFTER the matrix op (V7). B-operand = packed x directly: the 144
// v_pk_mul_f16 per pair-iter of the x⊗bary build are GONE (VALU-issue was the
// measured bottleneck). 9 independent depth-2 MFMA chains per group; chain starts
// read a shared never-written ZERO4 (no acc zero-init); ONE 36-reg acc array reused
// across the two groups (caps live accs at 36 -> 3 waves/SIMD preserved).
//
// K ordering: p = kbasis*64 + i (chunk c of 32: kbasis = c>>1, i = (c&1)*32 + [0,32)).
// Wave w owns output channels [w*16, w*16+16): A-frags = 18 x half8 = 72 regs (AGPRs).
//
// Pipeline (= V6): 2 groups per buffer, 3-buffer rotation, SINGLE barrier per iter
// (stage(t) targets buffer read at t-1), depth-2 counted vmcnt, steady WAITV(9),
// never 0 in loop. X staged via global_load_lds with READ-LINEAR LDS layout (the
// permutation lives in the per-lane global src address) -> conflict-free ds_read_b128.
//
// D layout (measured, m89): row = quad*4 + reg (channel), col = lane&15 (texture)
//   -> facet (4 consecutive textures) = shfl_xor 1,2 across lanes.

typedef _Float16 half8  __attribute__((ext_vector_type(8)));
typedef _Float16 h2     __attribute__((ext_vector_type(2)));
typedef __fp16   fp16x2 __attribute__((ext_vector_type(2)));
typedef float    f32x4  __attribute__((ext_vector_type(4)));

#define NGROUPS 100000   // 1.6M textures / 16 per group
#define NPAIRS  50000    // groups staged in pairs (8KB X contiguous)
#define FFACETS 400000
#define GRID1   768      // 3 blocks/CU x 256 CUs, exactly resident
#define LDSP    9472     // per buffer: X[0,8192) | BARY[8192,9344) | NTEX[9344,9376)

#define WAITV(N) asm volatile("s_waitcnt vmcnt(" #N ")" ::: "memory")
#define FENCE()  asm volatile("" ::: "memory")

union H8 { h2 h[4]; half8 v; };

static __device__ __forceinline__ h2 pkrtz(float a, float b) {
    fp16x2 r = __builtin_amdgcn_cvt_pkrtz(a, b);
    return __builtin_bit_cast(h2, r);
}

static __device__ __forceinline__ void gload16(const void* g, void* l) {
    __builtin_amdgcn_global_load_lds((const __attribute__((address_space(1))) void*)g,
                                     (__attribute__((address_space(3))) void*)l, 16, 0, 0);
}

// ---- kernel 1: swizzle W (fp32 [64][64][9]) -> f16 fragment order in ws, zero stats
__global__ __launch_bounds__(256) void prep_kernel(const float* __restrict__ W,
                                                   _Float16* __restrict__ wswz,
                                                   float* __restrict__ stats) {
    int idx = blockIdx.x * 256 + threadIdx.x;
    if (idx < 36864) {
        int j    = idx & 7;
        int lane = (idx >> 3) & 63;
        int mt   = (idx >> 9) & 3;        // which wave (channel tile)
        int c    = idx >> 11;             // K chunk 0..17
        int o    = mt * 16 + (lane & 15);
        int i    = (c & 1) * 32 + ((lane >> 4) << 3) + j;
        int kb   = c >> 1;
        wswz[idx] = (_Float16)W[(o * 64 + i) * 9 + kb];
    }
    if (idx < 128) stats[idx] = 0.0f;
}

// ---- kernel 2: fused GEMM + facet mean + bias + ReLU + BN-stat accumulation
__global__ __launch_bounds__(256, 3) void pass1_kernel(
    const float* __restrict__ X, const float* __restrict__ BARY,
    const _Float16* __restrict__ WSWZ, const float* __restrict__ BIAS,
    const int* __restrict__ NTEX, float* __restrict__ OUT,
    float* __restrict__ stats) {

    __shared__ __align__(16) char ldsbuf[3 * LDSP];
    __shared__ float sl_s[64];
    __shared__ float sl_s2[64];

    const int tid  = threadIdx.x;
    const int wave = tid >> 6;
    const int lane = tid & 63;
    const int col  = lane & 15;   // texture within group / MFMA column
    const int quad = lane >> 4;

    // A-operand: this wave's 16 output channels, all K. 72 regs (AGPRs), resident whole kernel.
    half8 wf[18];
#pragma unroll
    for (int c = 0; c < 18; ++c)
        wf[c] = *(const half8*)(WSWZ + ((size_t)(c * 4 + wave) * 64 + lane) * 8);

    // bias for this lane's 4 channels: ch = wave*16 + quad*4 + r
    const f32x4 biasv = *(const f32x4*)(BIAS + wave * 16 + quad * 4);

    // ---- stage-side constants: linear LDS dest, permuted per-lane global src
    const int xdst = (wave << 10) + (lane << 4);             // dest byte within a 4KB half
    const int xsrc = ((lane & 15) << 8) + ((lane >> 4) << 5) // texture row + channel quad
                   + ((wave & 1) << 4) + ((wave >> 1) << 7); // wave covers (j&1)*16+(j>>1)*128
    const char* Xb  = (const char*)X;
    const char* BAb = (const char*)BARY;
    const char* NTb = (const char*)NTEX;

    // ---- read-side constants: X reads are lane-linear (conflict-free b128)
    const int xrd = lane << 4;
    const int bco = 8192 + col * 36;                         // 16 distinct banks, 4-way bcast
    const int nco = 9344 + ((col >> 2) << 2);

    float sacc[4]  = {0.f, 0.f, 0.f, 0.f};
    float s2acc[4] = {0.f, 0.f, 0.f, 0.f};

    const int b = blockIdx.x;
    const int n = (NPAIRS - 1 - b) / GRID1 + 1;              // pairs for this block (uniform)

    const f32x4 ZERO4 = {0.f, 0.f, 0.f, 0.f};                // shared C-input, never written

    // 5 vmem ops per wave per STAGE (uniform across waves)
    auto STAGE = [&](char* S, int u) {
        const char* xs = Xb + (size_t)u * 8192;
        FENCE();
        gload16(xs + xsrc,        S + xdst);
        gload16(xs + 4096 + xsrc, S + 4096 + xdst);
        gload16(BAb + (size_t)u * 1152 + lane * 16, S + 8192 + lane * 16);
        if (lane < 8) gload16(BAb + (size_t)u * 1152 + 1024 + lane * 16, S + 9216 + lane * 16);
        if (lane < 2) gload16(NTb + (size_t)u * 32 + lane * 16,          S + 9344 + lane * 16);
        FENCE();
    };

    auto EPI = [&](f32x4 acc, float rc, int f) {
        f32x4 vv;
#pragma unroll
        for (int r = 0; r < 4; ++r) {
            float s = acc[r];
            s += __shfl_xor(s, 1);
            s += __shfl_xor(s, 2);
            s = s * rc + biasv[r];
            s = s > 0.f ? s : 0.f;
            vv[r] = s;
            sacc[r]  += s;         // every lane in the col-group holds same value:
            s2acc[r] += s * s;     // 4x overcount, corrected by 0.25 at the end
        }
        if ((col & 3) == 0)
            *(f32x4*)(OUT + (size_t)f * 64 + wave * 16 + quad * 4) = vv;
    };

    // ITER: [barrier][read buf L][stage into S][pack x][MFMA g0][fold g0][MFMA g1][fold g1][EPI]
    // Single barrier is safe: every wave consumes its ds_reads before reaching the NEXT
    // barrier, and S at iter t is the buffer that was read at t-1 (3-buffer rotation).
    auto ITER = [&](const char* L, char* S, int u, int upre, bool do_stage) {
        __builtin_amdgcn_s_barrier();          // caller did WAITV: stage(u) landed for all waves
        FENCE();
        // ---- LDS reads: 8x b128 lane-linear + 18x b32 bcast + 2x b32
        f32x4 r0[4], r1[4];
#pragma unroll
        for (int j = 0; j < 4; ++j) {
            r0[j] = *(const f32x4*)(L + (j << 10) + xrd);
            r1[j] = *(const f32x4*)(L + 4096 + (j << 10) + xrd);
        }
        float bF0[9], bF1[9];
#pragma unroll
        for (int k = 0; k < 9; ++k) bF0[k] = *(const float*)(L + bco + k * 4);
#pragma unroll
        for (int k = 0; k < 9; ++k) bF1[k] = *(const float*)(L + bco + 576 + k * 4);
        const int nt0 = *(const int*)(L + nco);
        const int nt1 = *(const int*)(L + nco + 16);

        if (do_stage) STAGE(S, upre);          // issued early; flies across 2 iterations

        // ---- pack x to f16 (B-operands built ONCE per group, reused by all 18 MFMAs)
        H8 xlo0, xhi0, xlo1, xhi1;
        xlo0.h[0] = pkrtz(r0[0][0], r0[0][1]);  xlo0.h[1] = pkrtz(r0[0][2], r0[0][3]);
        xlo0.h[2] = pkrtz(r0[1][0], r0[1][1]);  xlo0.h[3] = pkrtz(r0[1][2], r0[1][3]);
        xhi0.h[0] = pkrtz(r0[2][0], r0[2][1]);  xhi0.h[1] = pkrtz(r0[2][2], r0[2][3]);
        xhi0.h[2] = pkrtz(r0[3][0], r0[3][1]);  xhi0.h[3] = pkrtz(r0[3][2], r0[3][3]);
        xlo1.h[0] = pkrtz(r1[0][0], r1[0][1]);  xlo1.h[1] = pkrtz(r1[0][2], r1[0][3]);
        xlo1.h[2] = pkrtz(r1[1][0], r1[1][1]);  xlo1.h[3] = pkrtz(r1[1][2], r1[1][3]);
        xhi1.h[0] = pkrtz(r1[2][0], r1[2][1]);  xhi1.h[1] = pkrtz(r1[2][2], r1[2][3]);
        xhi1.h[2] = pkrtz(r1[3][0], r1[3][1]);  xhi1.h[3] = pkrtz(r1[3][2], r1[3][3]);
        const float rc0 = __builtin_amdgcn_rcpf((float)nt0);   // exact for pow2 counts
        const float rc1 = __builtin_amdgcn_rcpf((float)nt1);

        // ---- group 0: 18 MFMAs (9 independent depth-2 chains), then f32 bary fold
        f32x4 acc[9];                          // reused for group 1: caps live accs at 36
        __builtin_amdgcn_s_setprio(1);
#pragma unroll
        for (int kb = 0; kb < 9; ++kb) {
            f32x4 tmp = __builtin_amdgcn_mfma_f32_16x16x32_f16(wf[2 * kb],     xlo0.v, ZERO4, 0, 0, 0);
            acc[kb]   = __builtin_amdgcn_mfma_f32_16x16x32_f16(wf[2 * kb + 1], xhi0.v, tmp,   0, 0, 0);
        }
        __builtin_amdgcn_s_setprio(0);
        f32x4 accA;
#pragma unroll
        for (int r = 0; r < 4; ++r) {
            float s = bF0[0] * acc[0][r];
#pragma unroll
            for (int k = 1; k < 9; ++k) s = __builtin_fmaf(bF0[k], acc[k][r], s);
            accA[r] = s;
        }

        // ---- group 1 (same acc registers; fold-before-overwrite orders the reuse)
        __builtin_amdgcn_s_setprio(1);
#pragma unroll
        for (int kb = 0; kb < 9; ++kb) {
            f32x4 tmp = __builtin_amdgcn_mfma_f32_16x16x32_f16(wf[2 * kb],     xlo1.v, ZERO4, 0, 0, 0);
            acc[kb]   = __builtin_amdgcn_mfma_f32_16x16x32_f16(wf[2 * kb + 1], xhi1.v, tmp,   0, 0, 0);
        }
        __builtin_amdgcn_s_setprio(0);
        f32x4 accB;
#pragma unroll
        for (int r = 0; r < 4; ++r) {
            float s = bF1[0] * acc[0][r];
#pragma unroll
            for (int k = 1; k < 9; ++k) s = __builtin_fmaf(bF1[k], acc[k][r], s);
            accB[r] = s;
        }

        // ---- facet mean + bias + ReLU + stats + store (facet = 4 adjacent lanes)
        const int f0 = u * 8 + (col >> 2);
        EPI(accA, rc0, f0);
        EPI(accB, rc1, f0 + 4);
    };

    char* B0 = ldsbuf;
    char* B1 = ldsbuf + LDSP;
    char* B2 = ldsbuf + 2 * LDSP;

    // ---- software pipeline: 3-buffer rotation, stage(t) -> buffer read at t-1
    STAGE(B0, b);
    STAGE(B1, b + GRID1);
    WAITV(5); ITER(B0, B2, b,         b + 2 * GRID1, true);   // also drains wf prologue loads
    WAITV(7); ITER(B1, B0, b + GRID1, b + 3 * GRID1, true);
    char *rd = B2, *st = B1, *ot = B0;
    int t = 2;
    for (; t < n - 2; ++t) {
        WAITV(9);
        ITER(rd, st, b + t * GRID1, b + (t + 2) * GRID1, true);
        char* tmp = ot; ot = st; st = rd; rd = tmp;
    }
    WAITV(9); ITER(rd, st, b + t * GRID1, 0, false);
    { char* tmp = ot; ot = st; st = rd; rd = tmp; } ++t;
    WAITV(4); ITER(rd, st, b + t * GRID1, 0, false);

    // reduce stats across the 16 cols; channels partitioned by (wave,quad,r)
#pragma unroll
    for (int r = 0; r < 4; ++r) {
        float s = sacc[r], s2 = s2acc[r];
        s  += __shfl_xor(s, 1);  s  += __shfl_xor(s, 2);
        s  += __shfl_xor(s, 4);  s  += __shfl_xor(s, 8);
        s2 += __shfl_xor(s2, 1); s2 += __shfl_xor(s2, 2);
        s2 += __shfl_xor(s2, 4); s2 += __shfl_xor(s2, 8);
        if (col == 0) {
            sl_s [wave * 16 + quad * 4 + r] = s  * 0.25f;
            sl_s2[wave * 16 + quad * 4 + r] = s2 * 0.25f;
        }
    }
    __syncthreads();
    if (tid < 64)        atomicAdd(&stats[tid],      sl_s [tid]);
    else if (tid < 128)  atomicAdd(&stats[tid],      sl_s2[tid - 64]);
}

// ---- kernel 3: in-place batch-norm normalize on OUT
__global__ __launch_bounds__(256) void pass3_kernel(float* __restrict__ OUT,
    const float* __restrict__ stats, const float* __restrict__ gamma,
    const float* __restrict__ beta) {
    const int tid = threadIdx.x;
    const size_t l = (size_t)blockIdx.x * 256 + tid;
    const int c0 = ((int)l & 15) * 4;     // grid*256 is a multiple of 16 -> constant per thread
    float mu[4], sc[4], be[4];
    const float invF = 1.0f / (float)FFACETS;
#pragma unroll
    for (int u = 0; u < 4; ++u) {
        int ch = c0 + u;
        float m  = stats[ch] * invF;
        float va = stats[64 + ch] * invF - m * m;
        mu[u] = m;
        sc[u] = rsqrtf(va + 1e-3f) * gamma[ch];
        be[u] = beta[ch];
    }
    const size_t n4 = (size_t)FFACETS * 16;
    for (size_t i = l; i < n4; i += (size_t)gridDim.x * 256) {
        f32x4 v = ((f32x4*)OUT)[i];
#pragma unroll
        for (int u = 0; u < 4; ++u)
            v[u] = (v[u] - mu[u]) * sc[u] + be[u];
        ((f32x4*)OUT)[i] = v;
    }
}

extern "C" void kernel_launch(void* const* d_in, const int* in_sizes, int n_in,
                              void* d_out, int out_size, void* d_ws, size_t ws_size,
                              hipStream_t stream) {
    const float* X     = (const float*)d_in[0];
    const float* BARY  = (const float*)d_in[1];
    const float* W     = (const float*)d_in[2];
    const float* BIAS  = (const float*)d_in[3];
    const float* GAMMA = (const float*)d_in[4];
    const float* BETA  = (const float*)d_in[5];
    const int*   NTEX  = (const int*)d_in[6];
    float* OUT = (float*)d_out;

    _Float16* wswz = (_Float16*)d_ws;                       // 73728 B
    float* stats   = (float*)((char*)d_ws + 73728);         // 128 floats

    prep_kernel<<<144, 256, 0, stream>>>(W, wswz, stats);
    pass1_kernel<<<GRID1, 256, 0, stream>>>(X, BARY, wswz, BIAS, NTEX, OUT, stats);
    pass3_kernel<<<2048, 256, 0, stream>>>(OUT, stats, GAMMA, BETA);
}

// Round 7
// 1192.330 us; speedup vs baseline: 1.0034x; 1.0034x over previous
//
#include <hip/hip_runtime.h>

// F2FConv3d on MI355X.
// V8: contrib[t,o] = sum_kb bary[t,kb] * (W_kb · x[t]) with a STREAMING fold:
// per kb, a 2-MFMA chain (B-operand = packed x directly, zero VALU build) lands in
// one of TWO rotating f32x4 temps; the f32 bary-fold of kb runs while kb+1's MFMAs
// are in flight. Removes the 144 v_pk_mul_f16 + 18 bary-pkrtz per pair-iter that
// made V6 issue-bound, while keeping peak live accs at 8 regs (V7 materialized 36
// and spilled: FETCH 2.19GB). Register budget ~= V6 -> 3 waves/SIMD preserved.
//
// K ordering: p = kbasis*64 + i (chunk c of 32: kbasis = c>>1, i = (c&1)*32 + [0,32)).
// Wave w owns output channels [w*16, w*16+16): A-frags = 18 x half8 = 72 regs (AGPRs).
//
// Pipeline (= V6): 2 groups per buffer, 3-buffer rotation, SINGLE barrier per iter
// (stage(t) targets buffer read at t-1), depth-2 counted vmcnt, steady WAITV(9),
// never 0 in loop. X staged via global_load_lds with READ-LINEAR LDS layout (the
// permutation lives in the per-lane global src address) -> conflict-free ds_read_b128.
//
// D layout (measured, m89): row = quad*4 + reg (channel), col = lane&15 (texture)
//   -> facet (4 consecutive textures) = shfl_xor 1,2 across lanes.

typedef _Float16 half8  __attribute__((ext_vector_type(8)));
typedef _Float16 h2     __attribute__((ext_vector_type(2)));
typedef __fp16   fp16x2 __attribute__((ext_vector_type(2)));
typedef float    f32x4  __attribute__((ext_vector_type(4)));

#define NGROUPS 100000   // 1.6M textures / 16 per group
#define NPAIRS  50000    // groups staged in pairs (8KB X contiguous)
#define FFACETS 400000
#define GRID1   768      // 3 blocks/CU x 256 CUs, exactly resident
#define LDSP    9472     // per buffer: X[0,8192) | BARY[8192,9344) | NTEX[9344,9376)

#define WAITV(N) asm volatile("s_waitcnt vmcnt(" #N ")" ::: "memory")
#define FENCE()  asm volatile("" ::: "memory")

union H8 { h2 h[4]; half8 v; };

static __device__ __forceinline__ h2 pkrtz(float a, float b) {
    fp16x2 r = __builtin_amdgcn_cvt_pkrtz(a, b);
    return __builtin_bit_cast(h2, r);
}

static __device__ __forceinline__ void gload16(const void* g, void* l) {
    __builtin_amdgcn_global_load_lds((const __attribute__((address_space(1))) void*)g,
                                     (__attribute__((address_space(3))) void*)l, 16, 0, 0);
}

// ---- kernel 1: swizzle W (fp32 [64][64][9]) -> f16 fragment order in ws, zero stats
__global__ __launch_bounds__(256) void prep_kernel(const float* __restrict__ W,
                                                   _Float16* __restrict__ wswz,
                                                   float* __restrict__ stats) {
    int idx = blockIdx.x * 256 + threadIdx.x;
    if (idx < 36864) {
        int j    = idx & 7;
        int lane = (idx >> 3) & 63;
        int mt   = (idx >> 9) & 3;        // which wave (channel tile)
        int c    = idx >> 11;             // K chunk 0..17
        int o    = mt * 16 + (lane & 15);
        int i    = (c & 1) * 32 + ((lane >> 4) << 3) + j;
        int kb   = c >> 1;
        wswz[idx] = (_Float16)W[(o * 64 + i) * 9 + kb];
    }
    if (idx < 128) stats[idx] = 0.0f;
}

// ---- kernel 2: fused GEMM + facet mean + bias + ReLU + BN-stat accumulation
__global__ __launch_bounds__(256, 3) void pass1_kernel(
    const float* __restrict__ X, const float* __restrict__ BARY,
    const _Float16* __restrict__ WSWZ, const float* __restrict__ BIAS,
    const int* __restrict__ NTEX, float* __restrict__ OUT,
    float* __restrict__ stats) {

    __shared__ __align__(16) char ldsbuf[3 * LDSP];
    __shared__ float sl_s[64];
    __shared__ float sl_s2[64];

    const int tid  = threadIdx.x;
    const int wave = tid >> 6;
    const int lane = tid & 63;
    const int col  = lane & 15;   // texture within group / MFMA column
    const int quad = lane >> 4;

    // A-operand: this wave's 16 output channels, all K. 72 regs (AGPRs), resident whole kernel.
    half8 wf[18];
#pragma unroll
    for (int c = 0; c < 18; ++c)
        wf[c] = *(const half8*)(WSWZ + ((size_t)(c * 4 + wave) * 64 + lane) * 8);

    // bias for this lane's 4 channels: ch = wave*16 + quad*4 + r
    const f32x4 biasv = *(const f32x4*)(BIAS + wave * 16 + quad * 4);

    // ---- stage-side constants: linear LDS dest, permuted per-lane global src
    const int xdst = (wave << 10) + (lane << 4);             // dest byte within a 4KB half
    const int xsrc = ((lane & 15) << 8) + ((lane >> 4) << 5) // texture row + channel quad
                   + ((wave & 1) << 4) + ((wave >> 1) << 7); // wave covers (j&1)*16+(j>>1)*128
    const char* Xb  = (const char*)X;
    const char* BAb = (const char*)BARY;
    const char* NTb = (const char*)NTEX;

    // ---- read-side constants: X reads are lane-linear (conflict-free b128)
    const int xrd = lane << 4;
    const int bco = 8192 + col * 36;                         // 16 distinct banks, 4-way bcast
    const int nco = 9344 + ((col >> 2) << 2);

    float sacc[4]  = {0.f, 0.f, 0.f, 0.f};
    float s2acc[4] = {0.f, 0.f, 0.f, 0.f};

    const int b = blockIdx.x;
    const int n = (NPAIRS - 1 - b) / GRID1 + 1;              // pairs for this block (uniform)

    const f32x4 ZERO4 = {0.f, 0.f, 0.f, 0.f};                // shared C-input, never written

    // 5 vmem ops per wave per STAGE (uniform across waves)
    auto STAGE = [&](char* S, int u) {
        const char* xs = Xb + (size_t)u * 8192;
        FENCE();
        gload16(xs + xsrc,        S + xdst);
        gload16(xs + 4096 + xsrc, S + 4096 + xdst);
        gload16(BAb + (size_t)u * 1152 + lane * 16, S + 8192 + lane * 16);
        if (lane < 8) gload16(BAb + (size_t)u * 1152 + 1024 + lane * 16, S + 9216 + lane * 16);
        if (lane < 2) gload16(NTb + (size_t)u * 32 + lane * 16,          S + 9344 + lane * 16);
        FENCE();
    };

    auto EPI = [&](f32x4 acc, float rc, int f) {
        f32x4 vv;
#pragma unroll
        for (int r = 0; r < 4; ++r) {
            float s = acc[r];
            s += __shfl_xor(s, 1);
            s += __shfl_xor(s, 2);
            s = s * rc + biasv[r];
            s = s > 0.f ? s : 0.f;
            vv[r] = s;
            sacc[r]  += s;         // every lane in the col-group holds same value:
            s2acc[r] += s * s;     // 4x overcount, corrected by 0.25 at the end
        }
        if ((col & 3) == 0)
            *(f32x4*)(OUT + (size_t)f * 64 + wave * 16 + quad * 4) = vv;
    };

    // One group: 9x {2-MFMA chain -> streaming f32 bary-fold}. Two rotating temps:
    // P_kb lands in t[kb&1]; its fold overlaps P_{kb+1}'s MFMAs. Live accs: t[2]+acc.
    auto GRP = [&](half8 xlo, half8 xhi, const float* bF) -> f32x4 {
        f32x4 t[2];
        t[0] = __builtin_amdgcn_mfma_f32_16x16x32_f16(wf[0], xlo, ZERO4, 0, 0, 0);
        t[0] = __builtin_amdgcn_mfma_f32_16x16x32_f16(wf[1], xhi, t[0],  0, 0, 0);
        t[1] = __builtin_amdgcn_mfma_f32_16x16x32_f16(wf[2], xlo, ZERO4, 0, 0, 0);
        t[1] = __builtin_amdgcn_mfma_f32_16x16x32_f16(wf[3], xhi, t[1],  0, 0, 0);
        f32x4 acc;
#pragma unroll
        for (int r = 0; r < 4; ++r) acc[r] = bF[0] * t[0][r];
#pragma unroll
        for (int kb = 1; kb <= 8; ++kb) {
            if (kb <= 7) {
                const int s = (kb + 1) & 1;        // slot freed 2 steps ago
                t[s] = __builtin_amdgcn_mfma_f32_16x16x32_f16(wf[2 * (kb + 1)],     xlo, ZERO4, 0, 0, 0);
                t[s] = __builtin_amdgcn_mfma_f32_16x16x32_f16(wf[2 * (kb + 1) + 1], xhi, t[s],  0, 0, 0);
            }
            const int c = kb & 1;                  // slot holding P_kb
#pragma unroll
            for (int r = 0; r < 4; ++r) acc[r] = __builtin_fmaf(bF[kb], t[c][r], acc[r]);
        }
        return acc;
    };

    // ITER: [barrier][read buf L][stage into S][pack x][GRP g0][GRP g1][EPI x2]
    // Single barrier is safe: every wave consumes its ds_reads before reaching the NEXT
    // barrier, and S at iter t is the buffer that was read at t-1 (3-buffer rotation).
    auto ITER = [&](const char* L, char* S, int u, int upre, bool do_stage) {
        __builtin_amdgcn_s_barrier();          // caller did WAITV: stage(u) landed for all waves
        FENCE();
        // ---- LDS reads: 8x b128 lane-linear + 18x b32 bcast + 2x b32
        f32x4 r0[4], r1[4];
#pragma unroll
        for (int j = 0; j < 4; ++j) {
            r0[j] = *(const f32x4*)(L + (j << 10) + xrd);
            r1[j] = *(const f32x4*)(L + 4096 + (j << 10) + xrd);
        }
        float bF0[9], bF1[9];
#pragma unroll
        for (int k = 0; k < 9; ++k) bF0[k] = *(const float*)(L + bco + k * 4);
#pragma unroll
        for (int k = 0; k < 9; ++k) bF1[k] = *(const float*)(L + bco + 576 + k * 4);
        const int nt0 = *(const int*)(L + nco);
        const int nt1 = *(const int*)(L + nco + 16);

        if (do_stage) STAGE(S, upre);          // issued early; flies across 2 iterations

        // ---- pack x to f16 (B-operands built ONCE per group, reused by all 18 MFMAs)
        H8 xlo0, xhi0, xlo1, xhi1;
        xlo0.h[0] = pkrtz(r0[0][0], r0[0][1]);  xlo0.h[1] = pkrtz(r0[0][2], r0[0][3]);
        xlo0.h[2] = pkrtz(r0[1][0], r0[1][1]);  xlo0.h[3] = pkrtz(r0[1][2], r0[1][3]);
        xhi0.h[0] = pkrtz(r0[2][0], r0[2][1]);  xhi0.h[1] = pkrtz(r0[2][2], r0[2][3]);
        xhi0.h[2] = pkrtz(r0[3][0], r0[3][1]);  xhi0.h[3] = pkrtz(r0[3][2], r0[3][3]);
        xlo1.h[0] = pkrtz(r1[0][0], r1[0][1]);  xlo1.h[1] = pkrtz(r1[0][2], r1[0][3]);
        xlo1.h[2] = pkrtz(r1[1][0], r1[1][1]);  xlo1.h[3] = pkrtz(r1[1][2], r1[1][3]);
        xhi1.h[0] = pkrtz(r1[2][0], r1[2][1]);  xhi1.h[1] = pkrtz(r1[2][2], r1[2][3]);
        xhi1.h[2] = pkrtz(r1[3][0], r1[3][1]);  xhi1.h[3] = pkrtz(r1[3][2], r1[3][3]);
        const float rc0 = __builtin_amdgcn_rcpf((float)nt0);   // exact for pow2 counts
        const float rc1 = __builtin_amdgcn_rcpf((float)nt1);

        __builtin_amdgcn_s_setprio(1);
        f32x4 accA = GRP(xlo0.v, xhi0.v, bF0);
        f32x4 accB = GRP(xlo1.v, xhi1.v, bF1);
        __builtin_amdgcn_s_setprio(0);

        // ---- facet mean + bias + ReLU + stats + store (facet = 4 adjacent lanes)
        const int f0 = u * 8 + (col >> 2);
        EPI(accA, rc0, f0);
        EPI(accB, rc1, f0 + 4);
    };

    char* B0 = ldsbuf;
    char* B1 = ldsbuf + LDSP;
    char* B2 = ldsbuf + 2 * LDSP;

    // ---- software pipeline: 3-buffer rotation, stage(t) -> buffer read at t-1
    STAGE(B0, b);
    STAGE(B1, b + GRID1);
    WAITV(5); ITER(B0, B2, b,         b + 2 * GRID1, true);   // also drains wf prologue loads
    WAITV(7); ITER(B1, B0, b + GRID1, b + 3 * GRID1, true);
    char *rd = B2, *st = B1, *ot = B0;
    int t = 2;
    for (; t < n - 2; ++t) {
        WAITV(9);
        ITER(rd, st, b + t * GRID1, b + (t + 2) * GRID1, true);
        char* tmp = ot; ot = st; st = rd; rd = tmp;
    }
    WAITV(9); ITER(rd, st, b + t * GRID1, 0, false);
    { char* tmp = ot; ot = st; st = rd; rd = tmp; } ++t;
    WAITV(4); ITER(rd, st, b + t * GRID1, 0, false);

    // reduce stats across the 16 cols; channels partitioned by (wave,quad,r)
#pragma unroll
    for (int r = 0; r < 4; ++r) {
        float s = sacc[r], s2 = s2acc[r];
        s  += __shfl_xor(s, 1);  s  += __shfl_xor(s, 2);
        s  += __shfl_xor(s, 4);  s  += __shfl_xor(s, 8);
        s2 += __shfl_xor(s2, 1); s2 += __shfl_xor(s2, 2);
        s2 += __shfl_xor(s2, 4); s2 += __shfl_xor(s2, 8);
        if (col == 0) {
            sl_s [wave * 16 + quad * 4 + r] = s  * 0.25f;
            sl_s2[wave * 16 + quad * 4 + r] = s2 * 0.25f;
        }
    }
    __syncthreads();
    if (tid < 64)        atomicAdd(&stats[tid],      sl_s [tid]);
    else if (tid < 128)  atomicAdd(&stats[tid],      sl_s2[tid - 64]);
}

// ---- kernel 3: in-place batch-norm normalize on OUT
__global__ __launch_bounds__(256) void pass3_kernel(float* __restrict__ OUT,
    const float* __restrict__ stats, const float* __restrict__ gamma,
    const float* __restrict__ beta) {
    const int tid = threadIdx.x;
    const size_t l = (size_t)blockIdx.x * 256 + tid;
    const int c0 = ((int)l & 15) * 4;     // grid*256 is a multiple of 16 -> constant per thread
    float mu[4], sc[4], be[4];
    const float invF = 1.0f / (float)FFACETS;
#pragma unroll
    for (int u = 0; u < 4; ++u) {
        int ch = c0 + u;
        float m  = stats[ch] * invF;
        float va = stats[64 + ch] * invF - m * m;
        mu[u] = m;
        sc[u] = rsqrtf(va + 1e-3f) * gamma[ch];
        be[u] = beta[ch];
    }
    const size_t n4 = (size_t)FFACETS * 16;
    for (size_t i = l; i < n4; i += (size_t)gridDim.x * 256) {
        f32x4 v = ((f32x4*)OUT)[i];
#pragma unroll
        for (int u = 0; u < 4; ++u)
            v[u] = (v[u] - mu[u]) * sc[u] + be[u];
        ((f32x4*)OUT)[i] = v;
    }
}

extern "C" void kernel_launch(void* const* d_in, const int* in_sizes, int n_in,
                              void* d_out, int out_size, void* d_ws, size_t ws_size,
                              hipStream_t stream) {
    const float* X     = (const float*)d_in[0];
    const float* BARY  = (const float*)d_in[1];
    const float* W     = (const float*)d_in[2];
    const float* BIAS  = (const float*)d_in[3];
    const float* GAMMA = (const float*)d_in[4];
    const float* BETA  = (const float*)d_in[5];
    const int*   NTEX  = (const int*)d_in[6];
    float* OUT = (float*)d_out;

    _Float16* wswz = (_Float16*)d_ws;                       // 73728 B
    float* stats   = (float*)((char*)d_ws + 73728);         // 128 floats

    prep_kernel<<<144, 256, 0, stream>>>(W, wswz, stats);
    pass1_kernel<<<GRID1, 256, 0, stream>>>(X, BARY, wswz, BIAS, NTEX, OUT, stats);
    pass3_kernel<<<2048, 256, 0, stream>>>(OUT, stats, GAMMA, BETA);
}

// Round 8
// 855.998 us; speedup vs baseline: 1.3977x; 1.3929x over previous
//
#include <hip/hip_runtime.h>

// F2FConv3d on MI355X.
// V9 = V6 pipeline + STREAMING bary-fold with PINNED schedule.
// contrib[t,o] = sum_kb bary[t,kb] * (W_kb · x[t]). Per kb: a 4-MFMA window (both
// groups' depth-2 chains, B = packed x directly — zero VALU operand build), then
// sched_barrier(0), then the 8-FMA f32 fold, then sched_barrier(0). The pins cap
// liveness at 2 wf frags + 2 temps + 2 accs per window — V7/V8 let the scheduler
// hoist all 9 chain-starts, which spilled ~9 wf fragments to scratch and re-read
// them every iteration (FETCH 240MB -> 2.19GB, the measured 3.5x regression).
// Removes per pair-iter: 144 v_pk_mul_f16 + 18 bary-pkrtz; adds 72 f32 FMA.
//
// K ordering: p = kbasis*64 + i (chunk c of 32: kbasis = c>>1, i = (c&1)*32 + [0,32)).
// Wave w owns output channels [w*16, w*16+16): A-frags = 18 x half8 = 72 regs (AGPRs).
//
// Pipeline (= V6): 2 groups per buffer, 3-buffer rotation, SINGLE barrier per iter
// (stage(t) targets buffer read at t-1), depth-2 counted vmcnt, steady WAITV(9),
// never 0 in loop. X staged via global_load_lds with READ-LINEAR LDS layout (the
// permutation lives in the per-lane global src address) -> conflict-free ds_read_b128.
//
// D layout (measured, m89): row = quad*4 + reg (channel), col = lane&15 (texture)
//   -> facet (4 consecutive textures) = shfl_xor 1,2 across lanes.

typedef _Float16 half8  __attribute__((ext_vector_type(8)));
typedef _Float16 h2     __attribute__((ext_vector_type(2)));
typedef __fp16   fp16x2 __attribute__((ext_vector_type(2)));
typedef float    f32x4  __attribute__((ext_vector_type(4)));

#define NGROUPS 100000   // 1.6M textures / 16 per group
#define NPAIRS  50000    // groups staged in pairs (8KB X contiguous)
#define FFACETS 400000
#define GRID1   768      // 3 blocks/CU x 256 CUs, exactly resident
#define LDSP    9472     // per buffer: X[0,8192) | BARY[8192,9344) | NTEX[9344,9376)

#define WAITV(N) asm volatile("s_waitcnt vmcnt(" #N ")" ::: "memory")
#define FENCE()  asm volatile("" ::: "memory")
#define PIN()    __builtin_amdgcn_sched_barrier(0)

union H8 { h2 h[4]; half8 v; };

static __device__ __forceinline__ h2 pkrtz(float a, float b) {
    fp16x2 r = __builtin_amdgcn_cvt_pkrtz(a, b);
    return __builtin_bit_cast(h2, r);
}

static __device__ __forceinline__ void gload16(const void* g, void* l) {
    __builtin_amdgcn_global_load_lds((const __attribute__((address_space(1))) void*)g,
                                     (__attribute__((address_space(3))) void*)l, 16, 0, 0);
}

// ---- kernel 1: swizzle W (fp32 [64][64][9]) -> f16 fragment order in ws, zero stats
__global__ __launch_bounds__(256) void prep_kernel(const float* __restrict__ W,
                                                   _Float16* __restrict__ wswz,
                                                   float* __restrict__ stats) {
    int idx = blockIdx.x * 256 + threadIdx.x;
    if (idx < 36864) {
        int j    = idx & 7;
        int lane = (idx >> 3) & 63;
        int mt   = (idx >> 9) & 3;        // which wave (channel tile)
        int c    = idx >> 11;             // K chunk 0..17
        int o    = mt * 16 + (lane & 15);
        int i    = (c & 1) * 32 + ((lane >> 4) << 3) + j;
        int kb   = c >> 1;
        wswz[idx] = (_Float16)W[(o * 64 + i) * 9 + kb];
    }
    if (idx < 128) stats[idx] = 0.0f;
}

// ---- kernel 2: fused GEMM + facet mean + bias + ReLU + BN-stat accumulation
__global__ __launch_bounds__(256, 3) void pass1_kernel(
    const float* __restrict__ X, const float* __restrict__ BARY,
    const _Float16* __restrict__ WSWZ, const float* __restrict__ BIAS,
    const int* __restrict__ NTEX, float* __restrict__ OUT,
    float* __restrict__ stats) {

    __shared__ __align__(16) char ldsbuf[3 * LDSP];
    __shared__ float sl_s[64];
    __shared__ float sl_s2[64];

    const int tid  = threadIdx.x;
    const int wave = tid >> 6;
    const int lane = tid & 63;
    const int col  = lane & 15;   // texture within group / MFMA column
    const int quad = lane >> 4;

    // A-operand: this wave's 16 output channels, all K. 72 regs (AGPRs), resident whole kernel.
    half8 wf[18];
#pragma unroll
    for (int c = 0; c < 18; ++c)
        wf[c] = *(const half8*)(WSWZ + ((size_t)(c * 4 + wave) * 64 + lane) * 8);

    // bias for this lane's 4 channels: ch = wave*16 + quad*4 + r
    const f32x4 biasv = *(const f32x4*)(BIAS + wave * 16 + quad * 4);

    // ---- stage-side constants: linear LDS dest, permuted per-lane global src
    const int xdst = (wave << 10) + (lane << 4);             // dest byte within a 4KB half
    const int xsrc = ((lane & 15) << 8) + ((lane >> 4) << 5) // texture row + channel quad
                   + ((wave & 1) << 4) + ((wave >> 1) << 7); // wave covers (j&1)*16+(j>>1)*128
    const char* Xb  = (const char*)X;
    const char* BAb = (const char*)BARY;
    const char* NTb = (const char*)NTEX;

    // ---- read-side constants: X reads are lane-linear (conflict-free b128)
    const int xrd = lane << 4;
    const int bco = 8192 + col * 36;                         // 16 distinct banks, 4-way bcast
    const int nco = 9344 + ((col >> 2) << 2);

    float sacc[4]  = {0.f, 0.f, 0.f, 0.f};
    float s2acc[4] = {0.f, 0.f, 0.f, 0.f};

    const int b = blockIdx.x;
    const int n = (NPAIRS - 1 - b) / GRID1 + 1;              // pairs for this block (uniform)

    const f32x4 ZERO4 = {0.f, 0.f, 0.f, 0.f};                // shared C-input, never written

    // 5 vmem ops per wave per STAGE (uniform across waves)
    auto STAGE = [&](char* S, int u) {
        const char* xs = Xb + (size_t)u * 8192;
        FENCE();
        gload16(xs + xsrc,        S + xdst);
        gload16(xs + 4096 + xsrc, S + 4096 + xdst);
        gload16(BAb + (size_t)u * 1152 + lane * 16, S + 8192 + lane * 16);
        if (lane < 8) gload16(BAb + (size_t)u * 1152 + 1024 + lane * 16, S + 9216 + lane * 16);
        if (lane < 2) gload16(NTb + (size_t)u * 32 + lane * 16,          S + 9344 + lane * 16);
        FENCE();
    };

    auto EPI = [&](f32x4 acc, float rc, int f) {
        f32x4 vv;
#pragma unroll
        for (int r = 0; r < 4; ++r) {
            float s = acc[r];
            s += __shfl_xor(s, 1);
            s += __shfl_xor(s, 2);
            s = s * rc + biasv[r];
            s = s > 0.f ? s : 0.f;
            vv[r] = s;
            sacc[r]  += s;         // every lane in the col-group holds same value:
            s2acc[r] += s * s;     // 4x overcount, corrected by 0.25 at the end
        }
        if ((col & 3) == 0)
            *(f32x4*)(OUT + (size_t)f * 64 + wave * 16 + quad * 4) = vv;
    };

    // ITER: [barrier][read buf L][stage into S][pack x][9 pinned MFMA+fold windows][EPI x2]
    // Single barrier is safe: every wave consumes its ds_reads before reaching the NEXT
    // barrier, and S at iter t is the buffer that was read at t-1 (3-buffer rotation).
    auto ITER = [&](const char* L, char* S, int u, int upre, bool do_stage) {
        __builtin_amdgcn_s_barrier();          // caller did WAITV: stage(u) landed for all waves
        FENCE();
        // ---- LDS reads: 8x b128 lane-linear + 18x b32 bcast + 2x b32
        f32x4 r0[4], r1[4];
#pragma unroll
        for (int j = 0; j < 4; ++j) {
            r0[j] = *(const f32x4*)(L + (j << 10) + xrd);
            r1[j] = *(const f32x4*)(L + 4096 + (j << 10) + xrd);
        }
        float bF0[9], bF1[9];
#pragma unroll
        for (int k = 0; k < 9; ++k) bF0[k] = *(const float*)(L + bco + k * 4);
#pragma unroll
        for (int k = 0; k < 9; ++k) bF1[k] = *(const float*)(L + bco + 576 + k * 4);
        const int nt0 = *(const int*)(L + nco);
        const int nt1 = *(const int*)(L + nco + 16);

        if (do_stage) STAGE(S, upre);          // issued early; flies across 2 iterations

        // ---- pack x to f16 (B-operands built ONCE per group, reused by all 18 MFMAs)
        H8 xlo0, xhi0, xlo1, xhi1;
        xlo0.h[0] = pkrtz(r0[0][0], r0[0][1]);  xlo0.h[1] = pkrtz(r0[0][2], r0[0][3]);
        xlo0.h[2] = pkrtz(r0[1][0], r0[1][1]);  xlo0.h[3] = pkrtz(r0[1][2], r0[1][3]);
        xhi0.h[0] = pkrtz(r0[2][0], r0[2][1]);  xhi0.h[1] = pkrtz(r0[2][2], r0[2][3]);
        xhi0.h[2] = pkrtz(r0[3][0], r0[3][1]);  xhi0.h[3] = pkrtz(r0[3][2], r0[3][3]);
        xlo1.h[0] = pkrtz(r1[0][0], r1[0][1]);  xlo1.h[1] = pkrtz(r1[0][2], r1[0][3]);
        xlo1.h[2] = pkrtz(r1[1][0], r1[1][1]);  xlo1.h[3] = pkrtz(r1[1][2], r1[1][3]);
        xhi1.h[0] = pkrtz(r1[2][0], r1[2][1]);  xhi1.h[1] = pkrtz(r1[2][2], r1[2][3]);
        xhi1.h[2] = pkrtz(r1[3][0], r1[3][1]);  xhi1.h[3] = pkrtz(r1[3][2], r1[3][3]);
        const float rc0 = __builtin_amdgcn_rcpf((float)nt0);   // exact for pow2 counts
        const float rc1 = __builtin_amdgcn_rcpf((float)nt1);

        // ---- 9 pinned windows: {4 MFMA | PIN | 8 FMA fold | PIN}
        // Liveness per window: wf[2kb..2kb+1] + tA,tB + accA,accB — scheduler cannot
        // hoist later windows' MFMAs above this fold (the V7/V8 spill cause).
        f32x4 accA, accB;
        __builtin_amdgcn_s_setprio(1);
        {
            f32x4 tA = __builtin_amdgcn_mfma_f32_16x16x32_f16(wf[0], xlo0.v, ZERO4, 0, 0, 0);
            f32x4 tB = __builtin_amdgcn_mfma_f32_16x16x32_f16(wf[0], xlo1.v, ZERO4, 0, 0, 0);
            tA = __builtin_amdgcn_mfma_f32_16x16x32_f16(wf[1], xhi0.v, tA, 0, 0, 0);
            tB = __builtin_amdgcn_mfma_f32_16x16x32_f16(wf[1], xhi1.v, tB, 0, 0, 0);
            PIN();
#pragma unroll
            for (int r = 0; r < 4; ++r) { accA[r] = bF0[0] * tA[r]; accB[r] = bF1[0] * tB[r]; }
            PIN();
        }
#pragma unroll
        for (int kb = 1; kb < 9; ++kb) {
            f32x4 tA = __builtin_amdgcn_mfma_f32_16x16x32_f16(wf[2 * kb], xlo0.v, ZERO4, 0, 0, 0);
            f32x4 tB = __builtin_amdgcn_mfma_f32_16x16x32_f16(wf[2 * kb], xlo1.v, ZERO4, 0, 0, 0);
            tA = __builtin_amdgcn_mfma_f32_16x16x32_f16(wf[2 * kb + 1], xhi0.v, tA, 0, 0, 0);
            tB = __builtin_amdgcn_mfma_f32_16x16x32_f16(wf[2 * kb + 1], xhi1.v, tB, 0, 0, 0);
            PIN();
#pragma unroll
            for (int r = 0; r < 4; ++r) {
                accA[r] = __builtin_fmaf(bF0[kb], tA[r], accA[r]);
                accB[r] = __builtin_fmaf(bF1[kb], tB[r], accB[r]);
            }
            PIN();
        }
        __builtin_amdgcn_s_setprio(0);

        // ---- facet mean + bias + ReLU + stats + store (facet = 4 adjacent lanes)
        const int f0 = u * 8 + (col >> 2);
        EPI(accA, rc0, f0);
        EPI(accB, rc1, f0 + 4);
    };

    char* B0 = ldsbuf;
    char* B1 = ldsbuf + LDSP;
    char* B2 = ldsbuf + 2 * LDSP;

    // ---- software pipeline: 3-buffer rotation, stage(t) -> buffer read at t-1
    STAGE(B0, b);
    STAGE(B1, b + GRID1);
    WAITV(5); ITER(B0, B2, b,         b + 2 * GRID1, true);   // also drains wf prologue loads
    WAITV(7); ITER(B1, B0, b + GRID1, b + 3 * GRID1, true);
    char *rd = B2, *st = B1, *ot = B0;
    int t = 2;
    for (; t < n - 2; ++t) {
        WAITV(9);
        ITER(rd, st, b + t * GRID1, b + (t + 2) * GRID1, true);
        char* tmp = ot; ot = st; st = rd; rd = tmp;
    }
    WAITV(9); ITER(rd, st, b + t * GRID1, 0, false);
    { char* tmp = ot; ot = st; st = rd; rd = tmp; } ++t;
    WAITV(4); ITER(rd, st, b + t * GRID1, 0, false);

    // reduce stats across the 16 cols; channels partitioned by (wave,quad,r)
#pragma unroll
    for (int r = 0; r < 4; ++r) {
        float s = sacc[r], s2 = s2acc[r];
        s  += __shfl_xor(s, 1);  s  += __shfl_xor(s, 2);
        s  += __shfl_xor(s, 4);  s  += __shfl_xor(s, 8);
        s2 += __shfl_xor(s2, 1); s2 += __shfl_xor(s2, 2);
        s2 += __shfl_xor(s2, 4); s2 += __shfl_xor(s2, 8);
        if (col == 0) {
            sl_s [wave * 16 + quad * 4 + r] = s  * 0.25f;
            sl_s2[wave * 16 + quad * 4 + r] = s2 * 0.25f;
        }
    }
    __syncthreads();
    if (tid < 64)        atomicAdd(&stats[tid],      sl_s [tid]);
    else if (tid < 128)  atomicAdd(&stats[tid],      sl_s2[tid - 64]);
}

// ---- kernel 3: in-place batch-norm normalize on OUT
__global__ __launch_bounds__(256) void pass3_kernel(float* __restrict__ OUT,
    const float* __restrict__ stats, const float* __restrict__ gamma,
    const float* __restrict__ beta) {
    const int tid = threadIdx.x;
    const size_t l = (size_t)blockIdx.x * 256 + tid;
    const int c0 = ((int)l & 15) * 4;     // grid*256 is a multiple of 16 -> constant per thread
    float mu[4], sc[4], be[4];
    const float invF = 1.0f / (float)FFACETS;
#pragma unroll
    for (int u = 0; u < 4; ++u) {
        int ch = c0 + u;
        float m  = stats[ch] * invF;
        float va = stats[64 + ch] * invF - m * m;
        mu[u] = m;
        sc[u] = rsqrtf(va + 1e-3f) * gamma[ch];
        be[u] = beta[ch];
    }
    const size_t n4 = (size_t)FFACETS * 16;
    for (size_t i = l; i < n4; i += (size_t)gridDim.x * 256) {
        f32x4 v = ((f32x4*)OUT)[i];
#pragma unroll
        for (int u = 0; u < 4; ++u)
            v[u] = (v[u] - mu[u]) * sc[u] + be[u];
        ((f32x4*)OUT)[i] = v;
    }
}

extern "C" void kernel_launch(void* const* d_in, const int* in_sizes, int n_in,
                              void* d_out, int out_size, void* d_ws, size_t ws_size,
                              hipStream_t stream) {
    const float* X     = (const float*)d_in[0];
    const float* BARY  = (const float*)d_in[1];
    const float* W     = (const float*)d_in[2];
    const float* BIAS  = (const float*)d_in[3];
    const float* GAMMA = (const float*)d_in[4];
    const float* BETA  = (const float*)d_in[5];
    const int*   NTEX  = (const int*)d_in[6];
    float* OUT = (float*)d_out;

    _Float16* wswz = (_Float16*)d_ws;                       // 73728 B
    float* stats   = (float*)((char*)d_ws + 73728);         // 128 floats

    prep_kernel<<<144, 256, 0, stream>>>(W, wswz, stats);
    pass1_kernel<<<GRID1, 256, 0, stream>>>(X, BARY, wswz, BIAS, NTEX, OUT, stats);
    pass3_kernel<<<2048, 256, 0, stream>>>(OUT, stats, GAMMA, BETA);
}

// Round 9
// 701.700 us; speedup vs baseline: 1.7050x; 1.2199x over previous
//
#include <hip/hip_runtime.h>

// F2FConv3d on MI355X.
// V10 = V6 datapath, BARRIER-FREE: each wave owns a private double-buffered LDS
// region (2 x 4688 B; 12 waves/CU x 9.4KB = 114KB <= 160KB) and runs a self-paced
// pipeline — NO s_barrier in the loop. The 4 waves of a block process the same
// group stream (each its 16-channel tile) but stage independently; the 4x read
// redundancy is absorbed by L1/L2 (same lines, back-to-back), HBM unchanged.
//   stage(t+2) targets the buffer being read at t; safe because all LDS reads are
//   consumed in the pack phase, then WAITL0+sched_barrier pin the overwrite after.
// X staging is TA-friendly: each global_load_lds covers a CONTIGUOUS 1KB (16 cache
// lines vs 64 scattered before). Bank-conflict-free reads via XOR swizzle:
//   lds[B] = xg[B ^ (((B>>8)&7)<<4)]  (XOR lives in bits 6:4, 16B-granule aligned)
//   read addr for x[col][i..]: (col*256+g) ^ ((col&7)<<4) -> 8 lanes/granule = free.
// vmcnt ladder (per-iter queue [stage:5][store:1]): W(5), W(6), steady W(7),
// tail W(7) no-stage, W(2). Never 0 in the loop.
//
// contrib = (x ⊗ bary) @ Wflat as f16 MFMA 16x16x32; W A-frags = 18 x half8 = 72
// regs (AGPRs), resident whole kernel. 18 MFMAs as 2 independent 9-chains.
// K ordering: p = kbasis*64 + i (chunk c: kbasis = c>>1, i = (c&1)*32 + [0,32)).
// D layout (measured, m89): row = quad*4 + reg (channel), col = lane&15 (texture)
//   -> facet (4 consecutive textures) = shfl_xor 1,2 across lanes.

typedef _Float16 half8  __attribute__((ext_vector_type(8)));
typedef _Float16 h2     __attribute__((ext_vector_type(2)));
typedef __fp16   fp16x2 __attribute__((ext_vector_type(2)));
typedef float    f32x4  __attribute__((ext_vector_type(4)));

#define NGROUPS 100000   // 1.6M textures / 16 per group
#define FFACETS 400000
#define GRID1   768      // 3 blocks/CU x 256 CUs, exactly resident
#define LDSW    4688     // per wave-buffer: X[0,4096) | BARY[4096,4672) | NTEX[4672,4688)

#define WAITV(N) asm volatile("s_waitcnt vmcnt(" #N ")" ::: "memory")
#define WAITL0() asm volatile("s_waitcnt lgkmcnt(0)" ::: "memory")
#define FENCE()  asm volatile("" ::: "memory")
#define SB0()    __builtin_amdgcn_sched_barrier(0)

union H8 { h2 h[4]; half8 v; };

static __device__ __forceinline__ h2 pkrtz(float a, float b) {
    fp16x2 r = __builtin_amdgcn_cvt_pkrtz(a, b);
    return __builtin_bit_cast(h2, r);
}

static __device__ __forceinline__ void gload16(const void* g, void* l) {
    __builtin_amdgcn_global_load_lds((const __attribute__((address_space(1))) void*)g,
                                     (__attribute__((address_space(3))) void*)l, 16, 0, 0);
}

// ---- kernel 1: swizzle W (fp32 [64][64][9]) -> f16 fragment order in ws, zero stats
__global__ __launch_bounds__(256) void prep_kernel(const float* __restrict__ W,
                                                   _Float16* __restrict__ wswz,
                                                   float* __restrict__ stats) {
    int idx = blockIdx.x * 256 + threadIdx.x;
    if (idx < 36864) {
        int j    = idx & 7;
        int lane = (idx >> 3) & 63;
        int mt   = (idx >> 9) & 3;        // which wave (channel tile)
        int c    = idx >> 11;             // K chunk 0..17
        int o    = mt * 16 + (lane & 15);
        int i    = (c & 1) * 32 + ((lane >> 4) << 3) + j;
        int kb   = c >> 1;
        wswz[idx] = (_Float16)W[(o * 64 + i) * 9 + kb];
    }
    if (idx < 128) stats[idx] = 0.0f;
}

// ---- kernel 2: fused GEMM + facet mean + bias + ReLU + BN-stat accumulation
__global__ __launch_bounds__(256, 3) void pass1_kernel(
    const float* __restrict__ X, const float* __restrict__ BARY,
    const _Float16* __restrict__ WSWZ, const float* __restrict__ BIAS,
    const int* __restrict__ NTEX, float* __restrict__ OUT,
    float* __restrict__ stats) {

    __shared__ __align__(16) char ldsbuf[8 * LDSW];   // [wave][2][LDSW]
    __shared__ float sl_s[64];
    __shared__ float sl_s2[64];

    const int tid  = threadIdx.x;
    const int wave = tid >> 6;
    const int lane = tid & 63;
    const int col  = lane & 15;   // texture within group / MFMA column
    const int quad = lane >> 4;

    // A-operand: this wave's 16 output channels, all K. 72 regs (AGPRs), resident whole kernel.
    half8 wf[18];
#pragma unroll
    for (int c = 0; c < 18; ++c)
        wf[c] = *(const half8*)(WSWZ + ((size_t)(c * 4 + wave) * 64 + lane) * 8);

    // bias for this lane's 4 channels: ch = wave*16 + quad*4 + r
    const f32x4 biasv = *(const f32x4*)(BIAS + wave * 16 + quad * 4);
    FENCE(); SB0();   // wf + bias loads precede all staging in the vmcnt queue

    // ---- stage-side: per-lane XOR-swizzled-contiguous X source offsets
    //   instr j covers global [j*1024, j*1024+1024): src = j*1024 + ((lane*16) ^ (s<<4)),
    //   s = ((j*4)+(lane>>4))&7; LDS dest = S + j*1024 + lane*16 (linear, wave-uniform base)
    int xsoff[4];
#pragma unroll
    for (int j = 0; j < 4; ++j)
        xsoff[j] = (j << 10) + ((lane << 4) ^ ((((j << 2) + (lane >> 4)) & 7) << 4));
    const char* Xb  = (const char*)X;
    const char* BAb = (const char*)BARY;
    const char* NTb = (const char*)NTEX;

    // ---- read-side: swizzled X addresses (8 lanes/16B-granule -> 2/bank = free)
    int xrd[4];
#pragma unroll
    for (int j = 0; j < 4; ++j) {
        const int g = (quad << 5) + ((j & 1) << 4) + ((j >> 1) << 7);
        xrd[j] = (col << 8) + (g ^ ((col & 7) << 4));
    }
    const int bco = 4096 + col * 36;              // stride 36B: conflict-free
    const int nco = 4096 + 576 + ((col >> 2) << 2);

    float sacc[4]  = {0.f, 0.f, 0.f, 0.f};
    float s2acc[4] = {0.f, 0.f, 0.f, 0.f};

    const int b = blockIdx.x;
    const int n = (NGROUPS - 1 - b) / GRID1 + 1;  // iters for this block (>=130)

    char* B0 = ldsbuf + wave * (2 * LDSW);        // this wave's private buffers
    char* B1 = B0 + LDSW;

    // 5 vmem ops per STAGE (uniform across waves; lanes 37-63 masked off on the 5th)
    auto STAGE = [&](char* S, int u) {
        const char* xs = Xb + (size_t)u * 4096;
        FENCE();
        gload16(xs + xsoff[0], S);
        gload16(xs + xsoff[1], S + 1024);
        gload16(xs + xsoff[2], S + 2048);
        gload16(xs + xsoff[3], S + 3072);
        if (lane < 37) {    // lanes 0-35: BARY row; lane 36: the group's 4 NTEX ints
            const char* g = (lane < 36) ? (BAb + (size_t)u * 576 + lane * 16)
                                        : (NTb + (size_t)u * 16);
            gload16(g, S + 4096 + lane * 16);
        }
        FENCE();
    };

    auto EPI = [&](f32x4 acc, float rc, int f) {
        f32x4 vv;
#pragma unroll
        for (int r = 0; r < 4; ++r) {
            float s = acc[r];
            s += __shfl_xor(s, 1);
            s += __shfl_xor(s, 2);
            s = s * rc + biasv[r];
            s = s > 0.f ? s : 0.f;
            vv[r] = s;
            sacc[r]  += s;         // every lane in the col-group holds same value:
            s2acc[r] += s * s;     // 4x overcount, corrected by 0.25 at the end
        }
        if ((col & 3) == 0)
            *(f32x4*)(OUT + (size_t)f * 64 + wave * 16 + quad * 4) = vv;
    };

    // ITER: [reads of L][pack: consumes all LDS reads][WAITL0+SB0][stage t+2 into L]
    //       [18 MFMA, 2 chains][EPI+store].  Caller did the counted WAITV.
    auto ITER = [&](char* L, int u, int upre, bool do_stage) {
        f32x4 r[4];
#pragma unroll
        for (int j = 0; j < 4; ++j) r[j] = *(const f32x4*)(L + xrd[j]);
        float bF[9];
#pragma unroll
        for (int k = 0; k < 9; ++k) bF[k] = *(const float*)(L + bco + k * 4);
        const int nt = *(const int*)(L + nco);

        // ---- pack to f16 (consumes every LDS read -> lgkm naturally drained)
        H8 xlo, xhi;
        xlo.h[0] = pkrtz(r[0][0], r[0][1]);  xlo.h[1] = pkrtz(r[0][2], r[0][3]);
        xlo.h[2] = pkrtz(r[1][0], r[1][1]);  xlo.h[3] = pkrtz(r[1][2], r[1][3]);
        xhi.h[0] = pkrtz(r[2][0], r[2][1]);  xhi.h[1] = pkrtz(r[2][2], r[2][3]);
        xhi.h[2] = pkrtz(r[3][0], r[3][1]);  xhi.h[3] = pkrtz(r[3][2], r[3][3]);
        h2 bh[9];
#pragma unroll
        for (int k = 0; k < 9; ++k) bh[k] = pkrtz(bF[k], bF[k]);
        const float rc = __builtin_amdgcn_rcpf((float)nt);   // exact for pow2 counts

        WAITL0();            // all reads of L done before the overwrite below
        SB0();
        if (do_stage) STAGE(L, upre);   // t+2 -> same buffer; flies across 2 iters
        FENCE();

        // ---- 18 MFMAs as 2 independent 9-chains (even chunks -> acc0, odd -> acc1)
        f32x4 acc0, acc1;
        __builtin_amdgcn_s_setprio(1);
#pragma unroll
        for (int c = 0; c < 18; ++c) {
            const h2 bk = bh[c >> 1];
            H8 bf;
            if (c & 1) {
                bf.h[0] = xhi.h[0] * bk;  bf.h[1] = xhi.h[1] * bk;
                bf.h[2] = xhi.h[2] * bk;  bf.h[3] = xhi.h[3] * bk;
            } else {
                bf.h[0] = xlo.h[0] * bk;  bf.h[1] = xlo.h[1] * bk;
                bf.h[2] = xlo.h[2] * bk;  bf.h[3] = xlo.h[3] * bk;
            }
            if (c == 0)      acc0 = __builtin_amdgcn_mfma_f32_16x16x32_f16(wf[c], bf.v, (f32x4){0,0,0,0}, 0, 0, 0);
            else if (c == 1) acc1 = __builtin_amdgcn_mfma_f32_16x16x32_f16(wf[c], bf.v, (f32x4){0,0,0,0}, 0, 0, 0);
            else if (c & 1)  acc1 = __builtin_amdgcn_mfma_f32_16x16x32_f16(wf[c], bf.v, acc1, 0, 0, 0);
            else             acc0 = __builtin_amdgcn_mfma_f32_16x16x32_f16(wf[c], bf.v, acc0, 0, 0, 0);
        }
        __builtin_amdgcn_s_setprio(0);
        f32x4 acc;
#pragma unroll
        for (int r = 0; r < 4; ++r) acc[r] = acc0[r] + acc1[r];

        // ---- facet mean + bias + ReLU + stats + store (facet = 4 adjacent lanes)
        EPI(acc, rc, u * 4 + (col >> 2));
    };

    // ---- self-paced pipeline: depth-2, counted vmcnt, ZERO barriers
    STAGE(B0, b);
    STAGE(B1, b + GRID1);
    WAITV(5); ITER(B0, b,         b + 2 * GRID1, true);   // also drains wf/bias loads
    WAITV(6); ITER(B1, b + GRID1, b + 3 * GRID1, true);
    int t = 2;
    for (; t < n - 2; ++t) {
        WAITV(7);
        ITER((t & 1) ? B1 : B0, b + t * GRID1, b + (t + 2) * GRID1, true);
    }
    WAITV(7); ITER((t & 1) ? B1 : B0, b + t * GRID1, 0, false); ++t;   // t = n-2
    WAITV(2); ITER((t & 1) ? B1 : B0, b + t * GRID1, 0, false);        // t = n-1

    // reduce stats across the 16 cols; channels partitioned by (wave,quad,r)
#pragma unroll
    for (int r = 0; r < 4; ++r) {
        float s = sacc[r], s2 = s2acc[r];
        s  += __shfl_xor(s, 1);  s  += __shfl_xor(s, 2);
        s  += __shfl_xor(s, 4);  s  += __shfl_xor(s, 8);
        s2 += __shfl_xor(s2, 1); s2 += __shfl_xor(s2, 2);
        s2 += __shfl_xor(s2, 4); s2 += __shfl_xor(s2, 8);
        if (col == 0) {
            sl_s [wave * 16 + quad * 4 + r] = s  * 0.25f;
            sl_s2[wave * 16 + quad * 4 + r] = s2 * 0.25f;
        }
    }
    __syncthreads();
    if (tid < 64)        atomicAdd(&stats[tid],      sl_s [tid]);
    else if (tid < 128)  atomicAdd(&stats[tid],      sl_s2[tid - 64]);
}

// ---- kernel 3: in-place batch-norm normalize on OUT
__global__ __launch_bounds__(256) void pass3_kernel(float* __restrict__ OUT,
    const float* __restrict__ stats, const float* __restrict__ gamma,
    const float* __restrict__ beta) {
    const int tid = threadIdx.x;
    const size_t l = (size_t)blockIdx.x * 256 + tid;
    const int c0 = ((int)l & 15) * 4;     // grid*256 is a multiple of 16 -> constant per thread
    float mu[4], sc[4], be[4];
    const float invF = 1.0f / (float)FFACETS;
#pragma unroll
    for (int u = 0; u < 4; ++u) {
        int ch = c0 + u;
        float m  = stats[ch] * invF;
        float va = stats[64 + ch] * invF - m * m;
        mu[u] = m;
        sc[u] = rsqrtf(va + 1e-3f) * gamma[ch];
        be[u] = beta[ch];
    }
    const size_t n4 = (size_t)FFACETS * 16;
    for (size_t i = l; i < n4; i += (size_t)gridDim.x * 256) {
        f32x4 v = ((f32x4*)OUT)[i];
#pragma unroll
        for (int u = 0; u < 4; ++u)
            v[u] = (v[u] - mu[u]) * sc[u] + be[u];
        ((f32x4*)OUT)[i] = v;
    }
}

extern "C" void kernel_launch(void* const* d_in, const int* in_sizes, int n_in,
                              void* d_out, int out_size, void* d_ws, size_t ws_size,
                              hipStream_t stream) {
    const float* X     = (const float*)d_in[0];
    const float* BARY  = (const float*)d_in[1];
    const float* W     = (const float*)d_in[2];
    const float* BIAS  = (const float*)d_in[3];
    const float* GAMMA = (const float*)d_in[4];
    const float* BETA  = (const float*)d_in[5];
    const int*   NTEX  = (const int*)d_in[6];
    float* OUT = (float*)d_out;

    _Float16* wswz = (_Float16*)d_ws;                       // 73728 B
    float* stats   = (float*)((char*)d_ws + 73728);         // 128 floats

    prep_kernel<<<144, 256, 0, stream>>>(W, wswz, stats);
    pass1_kernel<<<GRID1, 256, 0, stream>>>(X, BARY, wswz, BIAS, NTEX, OUT, stats);
    pass3_kernel<<<2048, 256, 0, stream>>>(OUT, stats, GAMMA, BETA);
}